// Round 2
// baseline (243.274 us; speedup 1.0000x reference)
//
#include <hip/hip_runtime.h>
#include <hip/hip_bf16.h>
#include <stdint.h>
#include <stddef.h>

typedef __bf16 bf16;
typedef __bf16 bf16x8 __attribute__((ext_vector_type(8)));
typedef float f32x4 __attribute__((ext_vector_type(4)));

#define BATCH 4096
#define KIH 7808          // Wih K
#define KTOT 7936         // + 128 for Whh (h0 appended to x)
#define NG 512            // 4*LH gates
#define LH 128
#define HD 64
#define ED 128

// ---------------------------------------------------------------------------
// async global->LDS, 16B per lane (wave-uniform LDS base + lane*16 semantics)
// ---------------------------------------------------------------------------
typedef const __attribute__((address_space(1))) uint32_t* gas_ptr;
typedef __attribute__((address_space(3))) uint32_t* las_ptr;

__device__ __forceinline__ void async16(const void* g, void* l) {
    __builtin_amdgcn_global_load_lds((gas_ptr)g, (las_ptr)l, 16, 0, 0);
}

// ---------------------------------------------------------------------------
// Kernel 0: pack fp32 [Wih | Whh] -> bf16 Wcat[512][7936]
// ---------------------------------------------------------------------------
__global__ void convert_w(const float* __restrict__ Wih,
                          const float* __restrict__ Whh,
                          bf16* __restrict__ Wcat) {
    const int total = NG * KTOT;
    for (int idx = blockIdx.x * blockDim.x + threadIdx.x; idx < total;
         idx += gridDim.x * blockDim.x) {
        const int n = idx / KTOT;
        const int k = idx - n * KTOT;
        const float v = (k < KIH) ? Wih[(size_t)n * KIH + k]
                                  : Whh[(size_t)n * LH + (k - KIH)];
        Wcat[idx] = (bf16)v;
    }
}

// ---------------------------------------------------------------------------
// Kernel 1: build x = [ab_gather | mv_gather | num @ num_W.T + num_b | h0]
// (fp32 in, bf16 out), one block per batch row, 128 threads
// ---------------------------------------------------------------------------
__global__ void build_x(const int* __restrict__ ab_ids,
                        const int* __restrict__ mv_ids,
                        const float* __restrict__ numerical,
                        const float* __restrict__ h0,
                        const float* __restrict__ ab_emb,
                        const float* __restrict__ mv_emb,
                        const float* __restrict__ numW,
                        const float* __restrict__ numb,
                        bf16* __restrict__ x) {
    const int b = blockIdx.x;
    const int t = threadIdx.x;  // 0..127
    bf16* xr = x + (size_t)b * KTOT;

    __shared__ int ids[60];
    __shared__ float numr[84];
    if (t < 60) ids[t] = (t < 12) ? ab_ids[b * 12 + t] : mv_ids[b * 48 + (t - 12)];
    if (t < 84) numr[t] = numerical[(size_t)b * 84 + t];
    __syncthreads();

#pragma unroll
    for (int s = 0; s < 12; ++s)
        xr[s * ED + t] = (bf16)ab_emb[(size_t)ids[s] * ED + t];
#pragma unroll 4
    for (int s = 0; s < 48; ++s)
        xr[12 * ED + s * ED + t] = (bf16)mv_emb[(size_t)ids[12 + s] * ED + t];

    float acc = numb[t];
#pragma unroll 4
    for (int k = 0; k < 84; ++k)
        acc += numr[k] * numW[t * 84 + k];
    xr[60 * ED + t] = (bf16)acc;
    xr[KIH + t] = (bf16)h0[(size_t)b * LH + t];
}

// ---------------------------------------------------------------------------
// Kernel 2: gates += x @ Wcat.T   (M=4096, N=512, K=7936)
// 128x128 tile, BK=64, 4 waves, 4x4 16x16x32 bf16 MFMA per wave, split-K=4
// ---------------------------------------------------------------------------
__global__ void gemm_gates(const bf16* __restrict__ x,
                           const bf16* __restrict__ Wcat,
                           float* __restrict__ gates) {
    __shared__ bf16 As[128 * 64];
    __shared__ bf16 Bs[128 * 64];

    const int tid = threadIdx.x;
    const int w = tid >> 6;       // wave 0..3
    const int lane = tid & 63;
    const int bm = blockIdx.x;    // 0..31
    const int bn = blockIdx.y;    // 0..3
    const int bz = blockIdx.z;    // 0..3
    const int kt_beg = bz * 31;
    const int kt_end = kt_beg + 31;

    // staging geometry: issue j of wave w covers LDS bytes [(w*4+j)*1024, +1024)
    // = 8 tile-rows of 128B; lane covers row (lane>>3), kk = (lane&7)*8 elems
    const int srow = lane >> 3;
    const int skk = (lane & 7) * 8;

    f32x4 acc[4][4];
#pragma unroll
    for (int i = 0; i < 4; ++i)
#pragma unroll
        for (int j = 0; j < 4; ++j)
#pragma unroll
            for (int r = 0; r < 4; ++r) acc[i][j][r] = 0.f;

    const int m0 = (w & 1) * 64;   // wave's output row offset in tile
    const int n0 = (w >> 1) * 64;  // wave's output col offset in tile

    for (int kt = kt_beg; kt < kt_end; ++kt) {
        const int k0 = kt * 64;
        // ---- stage A tile (x rows) ----
#pragma unroll
        for (int j = 0; j < 4; ++j) {
            const int row = (w * 4 + j) * 8 + srow;
            const bf16* g = x + (size_t)(bm * 128 + row) * KTOT + (k0 + skk);
            async16(g, (void*)&As[((w * 4 + j) * 64 + lane) * 8]);
        }
        // ---- stage B tile (Wcat rows) ----
#pragma unroll
        for (int j = 0; j < 4; ++j) {
            const int row = (w * 4 + j) * 8 + srow;
            const bf16* g = Wcat + (size_t)(bn * 128 + row) * KTOT + (k0 + skk);
            async16(g, (void*)&Bs[((w * 4 + j) * 64 + lane) * 8]);
        }
        __syncthreads();

        // ---- compute: 2 k-steps of 32 ----
#pragma unroll
        for (int ks = 0; ks < 2; ++ks) {
            bf16x8 af[4], bfr[4];
            const int kk = ks * 32 + (lane >> 4) * 8;
#pragma unroll
            for (int t = 0; t < 4; ++t) {
                const int m = m0 + t * 16 + (lane & 15);
                af[t] = *(const bf16x8*)&As[m * 64 + kk];
                const int n = n0 + t * 16 + (lane & 15);
                bfr[t] = *(const bf16x8*)&Bs[n * 64 + kk];
            }
#pragma unroll
            for (int ti = 0; ti < 4; ++ti)
#pragma unroll
                for (int tj = 0; tj < 4; ++tj)
                    acc[ti][tj] = __builtin_amdgcn_mfma_f32_16x16x32_bf16(
                        af[ti], bfr[tj], acc[ti][tj], 0, 0, 0);
        }
        __syncthreads();
    }

    // ---- epilogue: atomic accumulate (split-K) ----
    const int mlo = (lane >> 4) * 4;
    const int nlo = lane & 15;
#pragma unroll
    for (int ti = 0; ti < 4; ++ti)
#pragma unroll
        for (int tj = 0; tj < 4; ++tj) {
            const int mg = bm * 128 + m0 + ti * 16 + mlo;
            const int ng = bn * 128 + n0 + tj * 16 + nlo;
            float* dst = gates + (size_t)mg * NG + ng;
#pragma unroll
            for (int r = 0; r < 4; ++r)
                atomicAdd(dst + (size_t)r * NG, acc[ti][tj][r]);
        }
}

// ---------------------------------------------------------------------------
// Kernel 3: LSTM pointwise + MLP head + softmax + masked renorm (all fp32)
// one block per batch row, 128 threads
// out layout: probs[B*9] | h1[B*128] | c1[B*128]
// ---------------------------------------------------------------------------
#define O_H1 (BATCH * 9)
#define O_C1 (BATCH * 9 + BATCH * LH)

__global__ void lstm_mlp(const float* __restrict__ gates,
                         const float* __restrict__ bih,
                         const float* __restrict__ bhh,
                         const float* __restrict__ c0,
                         const float* __restrict__ mask,
                         const float* __restrict__ W1,
                         const float* __restrict__ b1,
                         const float* __restrict__ W2,
                         const float* __restrict__ b2,
                         const float* __restrict__ Wa,
                         const float* __restrict__ ba,
                         float* __restrict__ out) {
    const int b = blockIdx.x;
    const int t = threadIdx.x;  // 0..127

    __shared__ float h1s[LH];
    __shared__ float us[HD];
    __shared__ float fs[ED];
    __shared__ float ls[9];
    __shared__ float es[9];
    __shared__ float red[2];

    const float* gr = gates + (size_t)b * NG;
    const float gi = gr[t] + bih[t] + bhh[t];
    const float gf = gr[LH + t] + bih[LH + t] + bhh[LH + t];
    const float gg = gr[2 * LH + t] + bih[2 * LH + t] + bhh[2 * LH + t];
    const float go = gr[3 * LH + t] + bih[3 * LH + t] + bhh[3 * LH + t];

    const float iv = 1.f / (1.f + expf(-gi));
    const float fv = 1.f / (1.f + expf(-gf));
    const float gv = tanhf(gg);
    const float ov = 1.f / (1.f + expf(-go));
    const float c1 = fv * c0[(size_t)b * LH + t] + iv * gv;
    const float h1 = ov * tanhf(c1);

    out[O_H1 + (size_t)b * LH + t] = h1;
    out[O_C1 + (size_t)b * LH + t] = c1;
    h1s[t] = h1;
    __syncthreads();

    if (t < HD) {
        float a = b1[t];
#pragma unroll 4
        for (int d = 0; d < LH; ++d) a += h1s[d] * W1[t * LH + d];
        us[t] = a > 0.f ? a : 0.f;
    }
    __syncthreads();

    {
        float a = b2[t];
#pragma unroll 4
        for (int j = 0; j < HD; ++j) a += us[j] * W2[t * HD + j];
        fs[t] = a;
    }
    __syncthreads();

    if (t < 9) {
        float a = ba[t];
#pragma unroll 4
        for (int d = 0; d < ED; ++d) a += fs[d] * Wa[t * ED + d];
        ls[t] = a;
    }
    __syncthreads();

    if (t == 0) {
        float m = ls[0];
        for (int a = 1; a < 9; ++a) m = fmaxf(m, ls[a]);
        red[0] = m;
    }
    __syncthreads();

    if (t < 9) es[t] = expf(ls[t] - red[0]);
    __syncthreads();

    if (t == 0) {
        float tot = 0.f, msum = 0.f;
        for (int a = 0; a < 9; ++a) {
            tot += es[a];
            msum += es[a] * mask[(size_t)b * 9 + a];
        }
        red[0] = tot;
        red[1] = msum;
    }
    __syncthreads();

    if (t < 9) {
        const float mv = mask[(size_t)b * 9 + t];
        const float o = (red[1] > 0.f) ? (es[t] * mv) / red[1] : es[t] / red[0];
        out[(size_t)b * 9 + t] = o;
    }
}

// ---------------------------------------------------------------------------
extern "C" void kernel_launch(void* const* d_in, const int* in_sizes, int n_in,
                              void* d_out, int out_size, void* d_ws, size_t ws_size,
                              hipStream_t stream) {
    const int* ab_ids = (const int*)d_in[0];
    const int* mv_ids = (const int*)d_in[1];
    const float* numerical = (const float*)d_in[2];
    const float* mask = (const float*)d_in[3];
    const float* h0 = (const float*)d_in[4];
    const float* c0 = (const float*)d_in[5];
    const float* ab_emb = (const float*)d_in[6];
    const float* mv_emb = (const float*)d_in[7];
    const float* numW = (const float*)d_in[8];
    const float* numb = (const float*)d_in[9];
    const float* Wih = (const float*)d_in[10];
    const float* Whh = (const float*)d_in[11];
    const float* bih = (const float*)d_in[12];
    const float* bhh = (const float*)d_in[13];
    const float* W1 = (const float*)d_in[14];
    const float* b1 = (const float*)d_in[15];
    const float* W2 = (const float*)d_in[16];
    const float* b2 = (const float*)d_in[17];
    const float* Wa = (const float*)d_in[18];
    const float* ba = (const float*)d_in[19];
    float* out = (float*)d_out;

    char* ws = (char*)d_ws;
    bf16* x = (bf16*)ws;                                  // 4096*7936*2 = 65,011,712 B
    bf16* Wcat = (bf16*)(ws + (size_t)65011712);          // 512*7936*2  =  8,126,464 B
    float* gates = (float*)(ws + (size_t)73138176);       // 4096*512*4  =  8,388,608 B
    // total ws use: 81,526,784 B

    hipMemsetAsync(gates, 0, (size_t)BATCH * NG * sizeof(float), stream);
    convert_w<<<4096, 256, 0, stream>>>(Wih, Whh, Wcat);
    build_x<<<BATCH, 128, 0, stream>>>(ab_ids, mv_ids, numerical, h0,
                                       ab_emb, mv_emb, numW, numb, x);
    gemm_gates<<<dim3(32, 4, 4), 256, 0, stream>>>(x, Wcat, gates);
    lstm_mlp<<<BATCH, 128, 0, stream>>>(gates, bih, bhh, c0, mask,
                                        W1, b1, W2, b2, Wa, ba, out);
}